// Round 3
// baseline (496.853 us; speedup 1.0000x reference)
//
#include <hip/hip_runtime.h>
#include <hip/hip_bf16.h>

#define NN 4096
#define NFEAT 256
#define NHID1 64
#define NHID2 32
#define NCLASS 8
#define NHEADS 4
#define NADJ 2
#define CAP 128

// ---------------------------------------------------------------------------
// Build per-row sorted neighbor lists from dense adjacency.
// One wave per row; 64 chunks of 64 columns; ballot+popcount compaction.
// grid: (NADJ*NN/4) blocks x 256 threads.
__global__ __launch_bounds__(256) void build_edges(const float* __restrict__ adj,
                                                   int* __restrict__ eidx,
                                                   int* __restrict__ ecnt) {
  const int wave = threadIdx.x >> 6;
  const int lane = threadIdx.x & 63;
  const int r = blockIdx.x * 4 + wave;  // g*NN + n
  const float* row = adj + (size_t)r * NN;
  int* out = eidx + (size_t)r * CAP;
  int base = 0;
  for (int c = 0; c < NN; c += 64) {
    const int j = c + lane;
    const bool hit = row[j] > 0.f;
    const unsigned long long m = __ballot(hit);
    if (hit) {
      const int pos = base + __popcll(m & ((1ull << lane) - 1ull));
      if (pos < CAP) out[pos] = j;
    }
    base += __popcll(m);
  }
  if (lane == 0) ecnt[r] = base < CAP ? base : CAP;
}

// ---------------------------------------------------------------------------
// Small GEMM, K-tiled: C[row, c] = act( A[row,:K] . B[:,c] + bias[c] )
// B tile (KT x NDIM) staged in <=16KB LDS. blockIdx.y = head with strides.
// Block covers 64 rows of A/C.
template <int KDIM, int NDIM, int ACT>
__global__ __launch_bounds__(256) void gemm_act(const float* __restrict__ A,
                                                const float* __restrict__ B,
                                                const float* __restrict__ bias,
                                                float* __restrict__ C,
                                                int bStride, int cStride) {
  constexpr int KT = 64;
  constexpr int RG = 256 / NDIM;   // row-groups covered per pass
  constexpr int RPT = 64 / RG;     // rows per thread
  const int b = blockIdx.y;
  B += (size_t)b * bStride;
  C += (size_t)b * cStride;
  __shared__ float Bs[KT * NDIM];  // <= 64*64*4 = 16 KB
  const int tid = threadIdx.x;
  const int c = tid % NDIM;
  const int rg = tid / NDIM;
  const int row0 = blockIdx.x * 64;
  float acc[RPT];
#pragma unroll
  for (int r = 0; r < RPT; ++r) acc[r] = 0.f;
  for (int kt = 0; kt < KDIM; kt += KT) {
    __syncthreads();
    for (int i = tid; i < KT * NDIM; i += 256) Bs[i] = B[kt * NDIM + i];
    __syncthreads();
#pragma unroll
    for (int r = 0; r < RPT; ++r) {
      const float* a = A + (size_t)(row0 + rg + r * RG) * KDIM + kt;
      float s = 0.f;
#pragma unroll 8
      for (int k = 0; k < KT; ++k) s += a[k] * Bs[k * NDIM + c];
      acc[r] += s;
    }
  }
#pragma unroll
  for (int r = 0; r < RPT; ++r) {
    float v = acc[r] + (bias ? bias[c] : 0.f);
    if (ACT == 1) v = v > 0.f ? v : (__expf(v) - 1.f);  // elu
    C[(size_t)(row0 + rg + r * RG) * NDIM + c] = v;
  }
}

// ---------------------------------------------------------------------------
// f_src[h,n] = Wh[h,n,:] . a[h,0,:], f_dst[h,n] = Wh[h,n,:] . a[h,1,:]
// One wave per n; grid (NN/4, NHEADS).
template <int O>
__global__ __launch_bounds__(256) void attn_coef(const float* __restrict__ Wh,
                                                 const float* __restrict__ a,
                                                 float* __restrict__ fsrc,
                                                 float* __restrict__ fdst) {
  const int wave = threadIdx.x >> 6;
  const int lane = threadIdx.x & 63;
  const int n = blockIdx.x * 4 + wave;
  const int h = blockIdx.y;
  float v = 0.f, as = 0.f, ad = 0.f;
  if (lane < O) {
    v = Wh[((size_t)h * NN + n) * O + lane];
    as = a[(h * 2 + 0) * O + lane];
    ad = a[(h * 2 + 1) * O + lane];
  }
  float s = v * as, d = v * ad;
  for (int off = 32; off; off >>= 1) {
    s += __shfl_xor(s, off);
    d += __shfl_xor(d, off);
  }
  if (lane == 0) {
    fsrc[h * NN + n] = s;
    fdst[h * NN + n] = d;
  }
}

// ---------------------------------------------------------------------------
// Sparse masked softmax + aggregation + ELU for one (n,h) per wave.
// grid (NN/4, NHEADS). Hout[n, h*O + o] = elu( sum_j att_j * Wh[h, m_j, o] )
template <int O>
__global__ __launch_bounds__(256) void aggregate(const float* __restrict__ Wh,
                                                 const float* __restrict__ fsrc,
                                                 const float* __restrict__ fdst,
                                                 const int* __restrict__ eidx,
                                                 const int* __restrict__ ecnt,
                                                 float* __restrict__ Hout) {
  __shared__ float wgt[4][CAP];
  __shared__ int midx[4][CAP];
  const int wave = threadIdx.x >> 6;
  const int lane = threadIdx.x & 63;
  const int n = blockIdx.x * 4 + wave;
  const int h = blockIdx.y;
  const int cnt = ecnt[n];
  const int* ei = eidx + (size_t)n * CAP;
  const float fs = fsrc[h * NN + n];
  float mx = -3.4e38f;
  for (int j = lane; j < cnt; j += 64) {
    const int m = ei[j];
    float e = fs + fdst[h * NN + m];
    e = e > 0.f ? e : 0.2f * e;  // leaky relu, alpha = 0.2
    midx[wave][j] = m;
    wgt[wave][j] = e;
    mx = fmaxf(mx, e);
  }
  for (int off = 32; off; off >>= 1) mx = fmaxf(mx, __shfl_xor(mx, off));
  __syncthreads();
  float sm = 0.f;
  for (int j = lane; j < cnt; j += 64) {
    const float w = __expf(wgt[wave][j] - mx);
    wgt[wave][j] = w;
    sm += w;
  }
  for (int off = 32; off; off >>= 1) sm += __shfl_xor(sm, off);
  __syncthreads();
  if (lane < O) {
    float acc = 0.f;
    for (int j = 0; j < cnt; ++j)
      acc += wgt[wave][j] * Wh[((size_t)h * NN + midx[wave][j]) * O + lane];
    float r = acc / sm;
    r = r > 0.f ? r : (__expf(r) - 1.f);  // elu
    Hout[(size_t)n * (NHEADS * O) + h * O + lane] = r;
  }
}

// ---------------------------------------------------------------------------
// logits = concat(o2_g0, o2_g1) @ Wf + bf ; log_softmax ; l1 = mean|Wf|.
// Output is FLOAT32 (reference output dtype), 32769 floats.
__global__ __launch_bounds__(256) void final_out(const float* __restrict__ out2,
                                                 const float* __restrict__ Wf,
                                                 const float* __restrict__ bfv,
                                                 float* __restrict__ out) {
  const int n = blockIdx.x * 256 + threadIdx.x;
  if (blockIdx.x == 0 && threadIdx.x == 0) {
    float s = 0.f;
    for (int i = 0; i < NCLASS * NADJ * NCLASS; ++i) s += fabsf(Wf[i]);
    out[NN * NCLASS] = s * (1.f / (NCLASS * NADJ * NCLASS));
  }
  float cat[16];
  const float* o0 = out2 + (size_t)n * NCLASS;
  const float* o1 = out2 + (size_t)NN * NCLASS + (size_t)n * NCLASS;
#pragma unroll
  for (int k = 0; k < 8; ++k) { cat[k] = o0[k]; cat[8 + k] = o1[k]; }
  float logit[8];
#pragma unroll
  for (int c = 0; c < 8; ++c) {
    float acc = bfv[c];
#pragma unroll
    for (int k = 0; k < 16; ++k) acc += cat[k] * Wf[k * 8 + c];
    logit[c] = acc;
  }
  float m = logit[0];
#pragma unroll
  for (int c = 1; c < 8; ++c) m = fmaxf(m, logit[c]);
  float s = 0.f;
#pragma unroll
  for (int c = 0; c < 8; ++c) s += __expf(logit[c] - m);
  const float lse = logf(s) + m;
#pragma unroll
  for (int c = 0; c < 8; ++c)
    out[(size_t)n * NCLASS + c] = logit[c] - lse;
}

// ---------------------------------------------------------------------------
extern "C" void kernel_launch(void* const* d_in, const int* in_sizes, int n_in,
                              void* d_out, int out_size, void* d_ws, size_t ws_size,
                              hipStream_t stream) {
  const float* x = (const float*)d_in[0];
  const float* adj = (const float*)d_in[1];
  const float* W1 = (const float*)d_in[2];
  const float* a1 = (const float*)d_in[3];
  const float* W2 = (const float*)d_in[4];
  const float* a2 = (const float*)d_in[5];
  const float* Wi1 = (const float*)d_in[6];
  const float* bi1 = (const float*)d_in[7];
  const float* Wi2 = (const float*)d_in[8];
  const float* bi2 = (const float*)d_in[9];
  const float* Wf = (const float*)d_in[10];
  const float* bfv = (const float*)d_in[11];
  float* out = (float*)d_out;

  char* ws = (char*)d_ws;
  int* eidx = (int*)ws;      ws += (size_t)NADJ * NN * CAP * 4;      // 4 MB
  int* ecnt = (int*)ws;      ws += (size_t)NADJ * NN * 4;
  float* Wh1 = (float*)ws;   ws += (size_t)NHEADS * NN * NHID1 * 4;  // 4 MB
  float* fs1 = (float*)ws;   ws += (size_t)NHEADS * NN * 4;
  float* fd1 = (float*)ws;   ws += (size_t)NHEADS * NN * 4;
  float* h1 = (float*)ws;    ws += (size_t)NN * NHEADS * NHID1 * 4;  // 4 MB
  float* x1 = (float*)ws;    ws += (size_t)NN * NHID1 * 4;           // 1 MB
  float* Wh2 = (float*)ws;   ws += (size_t)NHEADS * NN * NHID2 * 4;  // 2 MB
  float* fs2 = (float*)ws;   ws += (size_t)NHEADS * NN * 4;
  float* fd2 = (float*)ws;   ws += (size_t)NHEADS * NN * 4;
  float* h2 = (float*)ws;    ws += (size_t)NN * NHEADS * NHID2 * 4;  // 2 MB
  float* o2 = (float*)ws;    ws += (size_t)NADJ * NN * NCLASS * 4;

  build_edges<<<NADJ * NN / 4, 256, 0, stream>>>(adj, eidx, ecnt);

  for (int g = 0; g < NADJ; ++g) {
    const int* eg = eidx + (size_t)g * NN * CAP;
    const int* cg = ecnt + (size_t)g * NN;
    // GAT layer 1
    gemm_act<NFEAT, NHID1, 0><<<dim3(NN / 64, NHEADS), 256, 0, stream>>>(
        x, W1 + (size_t)g * NHEADS * NFEAT * NHID1, nullptr, Wh1,
        NFEAT * NHID1, NN * NHID1);
    attn_coef<NHID1><<<dim3(NN / 4, NHEADS), 256, 0, stream>>>(
        Wh1, a1 + (size_t)g * NHEADS * 2 * NHID1, fs1, fd1);
    aggregate<NHID1><<<dim3(NN / 4, NHEADS), 256, 0, stream>>>(
        Wh1, fs1, fd1, eg, cg, h1);
    // interlayer linear + elu
    gemm_act<NHEADS * NHID1, NHID1, 1><<<dim3(NN / 64, 1), 256, 0, stream>>>(
        h1, Wi1, bi1, x1, 0, 0);
    // GAT layer 2
    gemm_act<NHID1, NHID2, 0><<<dim3(NN / 64, NHEADS), 256, 0, stream>>>(
        x1, W2 + (size_t)g * NHEADS * NHID1 * NHID2, nullptr, Wh2,
        NHID1 * NHID2, NN * NHID2);
    attn_coef<NHID2><<<dim3(NN / 4, NHEADS), 256, 0, stream>>>(
        Wh2, a2 + (size_t)g * NHEADS * 2 * NHID2, fs2, fd2);
    aggregate<NHID2><<<dim3(NN / 4, NHEADS), 256, 0, stream>>>(
        Wh2, fs2, fd2, eg, cg, h2);
    // interlayer linear 2 + elu
    gemm_act<NHEADS * NHID2, NCLASS, 1><<<dim3(NN / 64, 1), 256, 0, stream>>>(
        h2, Wi2, bi2, o2 + (size_t)g * NN * NCLASS, 0, 0);
  }

  final_out<<<NN / 256, 256, 0, stream>>>(o2, Wf, bfv, out);
}

// Round 4
// 145.114 us; speedup vs baseline: 3.4239x; 3.4239x over previous
//
#include <hip/hip_runtime.h>
#include <hip/hip_bf16.h>

#define NN 4096
#define NFEAT 256
#define NHID1 64
#define NHID2 32
#define NCLASS 8
#define NHEADS 4
#define NADJ 2
#define CAP 128

// ---------------------------------------------------------------------------
// Build per-row neighbor lists from dense adjacency. One wave per row,
// float4 loads (1KB/wave/iter), 4 ballots per chunk. Order within a chunk is
// jumbled (interleaved by lane) — harmless: softmax/aggregation are
// set-semantics up to fp rounding.
__global__ __launch_bounds__(256) void build_edges(const float* __restrict__ adj,
                                                   int* __restrict__ eidx,
                                                   int* __restrict__ ecnt) {
  const int wave = threadIdx.x >> 6;
  const int lane = threadIdx.x & 63;
  const int r = blockIdx.x * 4 + wave;  // g*NN + n
  const float4* row = (const float4*)(adj + (size_t)r * NN);
  int* out = eidx + (size_t)r * CAP;
  int base = 0;
  for (int c = 0; c < NN; c += 256) {
    const float4 v = row[(c >> 2) + lane];
    const int j0 = c + lane * 4;
    const float vt[4] = {v.x, v.y, v.z, v.w};
#pragma unroll
    for (int t = 0; t < 4; ++t) {
      const bool hit = vt[t] > 0.f;
      const unsigned long long m = __ballot(hit);
      if (hit) {
        const int pos = base + __popcll(m & ((1ull << lane) - 1ull));
        if (pos < CAP) out[pos] = j0 + t;
      }
      base += __popcll(m);
    }
  }
  if (lane == 0) ecnt[r] = base < CAP ? base : CAP;
}

// ---------------------------------------------------------------------------
// Register-blocked tiled GEMM: C = act(A @ B + bias). Each thread computes
// 4 rows x 4 cols from LDS-staged tiles; A is staged TRANSPOSED so the inner
// loop is two ds_read_b128 feeding 16 FMAs. blockIdx.y = head, blockIdx.z = g.
template <int KDIM, int NDIM, int ACT>
__global__ __launch_bounds__(256) void gemm_tile(
    const float* __restrict__ A, const float* __restrict__ B,
    const float* __restrict__ bias, float* __restrict__ C,
    size_t asG, size_t bsH, size_t bsG, size_t csH, size_t csG) {
  constexpr int KT = 32;
  constexpr int TX = NDIM / 4;   // threads along cols
  constexpr int TY = 256 / TX;   // threads along rows
  constexpr int BR = TY * 4;     // rows per block (64 or 128)
  const int g = blockIdx.z, h = blockIdx.y;
  A += (size_t)g * asG;
  B += (size_t)g * bsG + (size_t)h * bsH;
  C += (size_t)g * csG + (size_t)h * csH;
  __shared__ float AsT[KT][BR + 4];   // +4 pad: bank-spread, keeps 16B align
  __shared__ float Bs[KT][NDIM + 4];
  const int tid = threadIdx.x;
  const int tx = tid % TX, ty = tid / TX;
  const int row0b = blockIdx.x * BR;
  const int c0 = tx * 4;
  float acc[4][4];
#pragma unroll
  for (int i = 0; i < 4; ++i)
#pragma unroll
    for (int j = 0; j < 4; ++j) acc[i][j] = 0.f;

  for (int kt = 0; kt < KDIM; kt += KT) {
    __syncthreads();
    for (int i = tid; i < BR * (KT / 4); i += 256) {
      const int r = i / (KT / 4), e = i % (KT / 4);
      const float4 v = *(const float4*)(A + (size_t)(row0b + r) * KDIM + kt + e * 4);
      AsT[e * 4 + 0][r] = v.x;
      AsT[e * 4 + 1][r] = v.y;
      AsT[e * 4 + 2][r] = v.z;
      AsT[e * 4 + 3][r] = v.w;
    }
    for (int i = tid; i < KT * (NDIM / 4); i += 256) {
      const int k = i / (NDIM / 4), cc = i % (NDIM / 4);
      *(float4*)&Bs[k][cc * 4] = *(const float4*)(B + (size_t)(kt + k) * NDIM + cc * 4);
    }
    __syncthreads();
#pragma unroll
    for (int k = 0; k < KT; ++k) {
      const float4 av = *(const float4*)&AsT[k][ty * 4];
      const float4 bv = *(const float4*)&Bs[k][c0];
      const float a4[4] = {av.x, av.y, av.z, av.w};
      const float b4[4] = {bv.x, bv.y, bv.z, bv.w};
#pragma unroll
      for (int i = 0; i < 4; ++i)
#pragma unroll
        for (int j = 0; j < 4; ++j) acc[i][j] += a4[i] * b4[j];
    }
  }
  float b4[4] = {0.f, 0.f, 0.f, 0.f};
  if (bias) {
    const float4 bb = *(const float4*)&bias[c0];
    b4[0] = bb.x; b4[1] = bb.y; b4[2] = bb.z; b4[3] = bb.w;
  }
#pragma unroll
  for (int i = 0; i < 4; ++i) {
    const int row = row0b + ty * 4 + i;
    float4 o;
    float* op = (float*)&o;
#pragma unroll
    for (int j = 0; j < 4; ++j) {
      float v = acc[i][j] + b4[j];
      if (ACT == 1) v = v > 0.f ? v : (__expf(v) - 1.f);  // elu
      op[j] = v;
    }
    *(float4*)&C[(size_t)row * NDIM + c0] = o;
  }
}

// ---------------------------------------------------------------------------
// Tail GEMM: [NN,128] @ [128,8] + bias, elu. 32 rows/block, LDS-staged A,B.
__global__ __launch_bounds__(256) void gemm_small8(const float* __restrict__ A,
                                                   const float* __restrict__ B,
                                                   const float* __restrict__ bias,
                                                   float* __restrict__ C) {
  constexpr int K = 128;
  const int g = blockIdx.z;
  A += (size_t)g * NN * K;
  C += (size_t)g * NN * NCLASS;
  __shared__ float As[32][K + 4];
  __shared__ float Bs[K][NCLASS];
  const int tid = threadIdx.x;
  const int row0 = blockIdx.x * 32;
  for (int i = tid; i < 32 * (K / 4); i += 256) {
    const int r = i / (K / 4), e = i % (K / 4);
    *(float4*)&As[r][e * 4] = *(const float4*)(A + (size_t)(row0 + r) * K + e * 4);
  }
  for (int i = tid; i < K * NCLASS / 4; i += 256) {
    const int k = i / 2, cc = i % 2;
    *(float4*)&Bs[k][cc * 4] = *(const float4*)(B + k * NCLASS + cc * 4);
  }
  __syncthreads();
  const int c = tid & 7, r = tid >> 3;
  float acc = 0.f;
#pragma unroll 8
  for (int k = 0; k < K; ++k) acc += As[r][k] * Bs[k][c];
  float v = acc + bias[c];
  v = v > 0.f ? v : (__expf(v) - 1.f);  // elu
  C[(size_t)(row0 + r) * NCLASS + c] = v;
}

// ---------------------------------------------------------------------------
// f_src[g,h,n] = Wh[g,h,n,:] . a[g,h,0,:], f_dst likewise with a[g,h,1,:].
// One wave per n; grid (NN/4, NHEADS, NADJ).
template <int O>
__global__ __launch_bounds__(256) void attn_coef(const float* __restrict__ Wh,
                                                 const float* __restrict__ a,
                                                 float* __restrict__ fsrc,
                                                 float* __restrict__ fdst) {
  const int wave = threadIdx.x >> 6;
  const int lane = threadIdx.x & 63;
  const int n = blockIdx.x * 4 + wave;
  const int gh = blockIdx.z * NHEADS + blockIdx.y;
  Wh += (size_t)gh * NN * O;
  a += (size_t)gh * 2 * O;
  float v = 0.f, as = 0.f, ad = 0.f;
  if (lane < O) {
    v = Wh[(size_t)n * O + lane];
    as = a[lane];
    ad = a[O + lane];
  }
  float s = v * as, d = v * ad;
  for (int off = 32; off; off >>= 1) {
    s += __shfl_xor(s, off);
    d += __shfl_xor(d, off);
  }
  if (lane == 0) {
    fsrc[(size_t)gh * NN + n] = s;
    fdst[(size_t)gh * NN + n] = d;
  }
}

// ---------------------------------------------------------------------------
// Sparse masked softmax + aggregation + ELU for one (n,h,g) per wave.
// Hout[g, n, h*O + o] = elu( sum_j att_j * Wh[g, h, m_j, o] )
template <int O>
__global__ __launch_bounds__(256) void aggregate(const float* __restrict__ Wh,
                                                 const float* __restrict__ fsrc,
                                                 const float* __restrict__ fdst,
                                                 const int* __restrict__ eidx,
                                                 const int* __restrict__ ecnt,
                                                 float* __restrict__ Hout) {
  __shared__ float wgt[4][CAP];
  __shared__ int midx[4][CAP];
  const int wave = threadIdx.x >> 6;
  const int lane = threadIdx.x & 63;
  const int n = blockIdx.x * 4 + wave;
  const int h = blockIdx.y, g = blockIdx.z;
  const int gh = g * NHEADS + h;
  Wh += (size_t)gh * NN * O;
  const int cnt = ecnt[(size_t)g * NN + n];
  const int* ei = eidx + (size_t)(g * NN + n) * CAP;
  const float fs = fsrc[(size_t)gh * NN + n];
  const float* fd = fdst + (size_t)gh * NN;
  float mx = -3.4e38f;
  for (int j = lane; j < cnt; j += 64) {
    const int m = ei[j];
    float e = fs + fd[m];
    e = e > 0.f ? e : 0.2f * e;  // leaky relu, alpha = 0.2
    midx[wave][j] = m;
    wgt[wave][j] = e;
    mx = fmaxf(mx, e);
  }
  for (int off = 32; off; off >>= 1) mx = fmaxf(mx, __shfl_xor(mx, off));
  float sm = 0.f;
  for (int j = lane; j < cnt; j += 64) {
    const float w = __expf(wgt[wave][j] - mx);
    wgt[wave][j] = w;
    sm += w;
  }
  for (int off = 32; off; off >>= 1) sm += __shfl_xor(sm, off);
  if (lane < O) {
    float acc = 0.f;
    for (int j = 0; j < cnt; ++j)
      acc += wgt[wave][j] * Wh[(size_t)midx[wave][j] * O + lane];
    float r = acc / sm;
    r = r > 0.f ? r : (__expf(r) - 1.f);  // elu
    Hout[(size_t)g * NN * (NHEADS * O) + (size_t)n * (NHEADS * O) + h * O + lane] = r;
  }
}

// ---------------------------------------------------------------------------
// logits = concat(o2_g0, o2_g1) @ Wf + bf ; log_softmax ; l1 = mean|Wf|.
// Output: 32769 float32 (32768 log-probs + l1 scalar).
__global__ __launch_bounds__(256) void final_out(const float* __restrict__ out2,
                                                 const float* __restrict__ Wf,
                                                 const float* __restrict__ bfv,
                                                 float* __restrict__ out) {
  const int n = blockIdx.x * 256 + threadIdx.x;
  if (blockIdx.x == 0 && threadIdx.x == 0) {
    float s = 0.f;
    for (int i = 0; i < NCLASS * NADJ * NCLASS; ++i) s += fabsf(Wf[i]);
    out[NN * NCLASS] = s * (1.f / (NCLASS * NADJ * NCLASS));
  }
  float cat[16];
  const float* o0 = out2 + (size_t)n * NCLASS;
  const float* o1 = out2 + (size_t)NN * NCLASS + (size_t)n * NCLASS;
#pragma unroll
  for (int k = 0; k < 8; ++k) { cat[k] = o0[k]; cat[8 + k] = o1[k]; }
  float logit[8];
#pragma unroll
  for (int c = 0; c < 8; ++c) {
    float acc = bfv[c];
#pragma unroll
    for (int k = 0; k < 16; ++k) acc += cat[k] * Wf[k * 8 + c];
    logit[c] = acc;
  }
  float m = logit[0];
#pragma unroll
  for (int c = 1; c < 8; ++c) m = fmaxf(m, logit[c]);
  float s = 0.f;
#pragma unroll
  for (int c = 0; c < 8; ++c) s += __expf(logit[c] - m);
  const float lse = logf(s) + m;
#pragma unroll
  for (int c = 0; c < 8; ++c)
    out[(size_t)n * NCLASS + c] = logit[c] - lse;
}

// ---------------------------------------------------------------------------
extern "C" void kernel_launch(void* const* d_in, const int* in_sizes, int n_in,
                              void* d_out, int out_size, void* d_ws, size_t ws_size,
                              hipStream_t stream) {
  const float* x = (const float*)d_in[0];
  const float* adj = (const float*)d_in[1];
  const float* W1 = (const float*)d_in[2];
  const float* a1 = (const float*)d_in[3];
  const float* W2 = (const float*)d_in[4];
  const float* a2 = (const float*)d_in[5];
  const float* Wi1 = (const float*)d_in[6];
  const float* bi1 = (const float*)d_in[7];
  const float* Wi2 = (const float*)d_in[8];
  const float* bi2 = (const float*)d_in[9];
  const float* Wf = (const float*)d_in[10];
  const float* bfv = (const float*)d_in[11];
  float* out = (float*)d_out;

  char* ws = (char*)d_ws;
  int* eidx = (int*)ws;     ws += (size_t)NADJ * NN * CAP * 4;           // 4 MB
  int* ecnt = (int*)ws;     ws += (size_t)NADJ * NN * 4;
  float* Wh1 = (float*)ws;  ws += (size_t)NADJ * NHEADS * NN * NHID1 * 4;  // 8 MB
  float* fs1 = (float*)ws;  ws += (size_t)NADJ * NHEADS * NN * 4;
  float* fd1 = (float*)ws;  ws += (size_t)NADJ * NHEADS * NN * 4;
  float* h1 = (float*)ws;   ws += (size_t)NADJ * NN * NHEADS * NHID1 * 4;  // 8 MB
  float* x1 = (float*)ws;   ws += (size_t)NADJ * NN * NHID1 * 4;           // 2 MB
  float* Wh2 = (float*)ws;  ws += (size_t)NADJ * NHEADS * NN * NHID2 * 4;  // 4 MB
  float* fs2 = (float*)ws;  ws += (size_t)NADJ * NHEADS * NN * 4;
  float* fd2 = (float*)ws;  ws += (size_t)NADJ * NHEADS * NN * 4;
  float* h2 = (float*)ws;   ws += (size_t)NADJ * NN * NHEADS * NHID2 * 4;  // 4 MB
  float* o2 = (float*)ws;   ws += (size_t)NADJ * NN * NCLASS * 4;

  build_edges<<<NADJ * NN / 4, 256, 0, stream>>>(adj, eidx, ecnt);

  // ---- layer 1 (both graphs via blockIdx.z) ----
  gemm_tile<NFEAT, NHID1, 0><<<dim3(NN / 64, NHEADS, NADJ), 256, 0, stream>>>(
      x, W1, nullptr, Wh1,
      /*asG*/ 0, /*bsH*/ (size_t)NFEAT * NHID1, /*bsG*/ (size_t)NHEADS * NFEAT * NHID1,
      /*csH*/ (size_t)NN * NHID1, /*csG*/ (size_t)NHEADS * NN * NHID1);
  attn_coef<NHID1><<<dim3(NN / 4, NHEADS, NADJ), 256, 0, stream>>>(Wh1, a1, fs1, fd1);
  aggregate<NHID1><<<dim3(NN / 4, NHEADS, NADJ), 256, 0, stream>>>(
      Wh1, fs1, fd1, eidx, ecnt, h1);
  gemm_tile<NHEADS * NHID1, NHID1, 1><<<dim3(NN / 64, 1, NADJ), 256, 0, stream>>>(
      h1, Wi1, bi1, x1,
      /*asG*/ (size_t)NN * NHEADS * NHID1, /*bsH*/ 0, /*bsG*/ 0,
      /*csH*/ 0, /*csG*/ (size_t)NN * NHID1);

  // ---- layer 2 ----
  gemm_tile<NHID1, NHID2, 0><<<dim3(NN / 128, NHEADS, NADJ), 256, 0, stream>>>(
      x1, W2, nullptr, Wh2,
      /*asG*/ (size_t)NN * NHID1, /*bsH*/ (size_t)NHID1 * NHID2,
      /*bsG*/ (size_t)NHEADS * NHID1 * NHID2,
      /*csH*/ (size_t)NN * NHID2, /*csG*/ (size_t)NHEADS * NN * NHID2);
  attn_coef<NHID2><<<dim3(NN / 4, NHEADS, NADJ), 256, 0, stream>>>(Wh2, a2, fs2, fd2);
  aggregate<NHID2><<<dim3(NN / 4, NHEADS, NADJ), 256, 0, stream>>>(
      Wh2, fs2, fd2, eidx, ecnt, h2);
  gemm_small8<<<dim3(NN / 32, 1, NADJ), 256, 0, stream>>>(h2, Wi2, bi2, o2);

  final_out<<<NN / 256, 256, 0, stream>>>(o2, Wf, bfv, out);
}

// Round 5
// 122.411 us; speedup vs baseline: 4.0589x; 1.1855x over previous
//
#include <hip/hip_runtime.h>
#include <hip/hip_bf16.h>

#define NN 4096
#define NFEAT 256
#define NHID1 64
#define NHID2 32
#define NCLASS 8
#define NHEADS 4
#define NADJ 2
#define CAP 128

// ---------------------------------------------------------------------------
// Build per-row neighbor lists from dense adjacency. One wave per row,
// float4 loads, 4 ballots per 256-col chunk. Order within a chunk is lane-
// interleaved (harmless: aggregation is set-semantics up to fp rounding).
__global__ __launch_bounds__(256) void build_edges(const float* __restrict__ adj,
                                                   int* __restrict__ eidx,
                                                   int* __restrict__ ecnt) {
  const int wave = threadIdx.x >> 6;
  const int lane = threadIdx.x & 63;
  const int r = blockIdx.x * 4 + wave;  // g*NN + n
  const float4* row = (const float4*)(adj + (size_t)r * NN);
  int* out = eidx + (size_t)r * CAP;
  int base = 0;
  for (int c = 0; c < NN; c += 256) {
    const float4 v = row[(c >> 2) + lane];
    const int j0 = c + lane * 4;
    const float vt[4] = {v.x, v.y, v.z, v.w};
#pragma unroll
    for (int t = 0; t < 4; ++t) {
      const bool hit = vt[t] > 0.f;
      const unsigned long long m = __ballot(hit);
      if (hit) {
        const int pos = base + __popcll(m & ((1ull << lane) - 1ull));
        if (pos < CAP) out[pos] = j0 + t;
      }
      base += __popcll(m);
    }
  }
  if (lane == 0) ecnt[r] = base < CAP ? base : CAP;
}

// ---------------------------------------------------------------------------
// Register-blocked tiled GEMM: C = act(A @ B + bias), optionally fused with
// the GAT attention-coefficient dot products (COEF=1):
//   fsrc[gh*NN+row] = C_row . a[gh,0,:],  fdst = C_row . a[gh,1,:]
// computed via __shfl_xor tree across the TX lanes holding the row.
// Each thread computes RPTY rows x 4 cols. A staged transposed in LDS.
template <int KDIM, int NDIM, int RPTY, int ACT, int COEF>
__global__ __launch_bounds__(256) void gemm_tile(
    const float* __restrict__ A, const float* __restrict__ B,
    const float* __restrict__ bias, float* __restrict__ C,
    const float* __restrict__ av, float* __restrict__ fsrc,
    float* __restrict__ fdst,
    size_t asG, size_t bsH, size_t bsG, size_t csH, size_t csG) {
  constexpr int KT = 32;
  constexpr int TX = NDIM / 4;     // threads along cols
  constexpr int TY = 256 / TX;     // thread groups along rows
  constexpr int BR = TY * RPTY;    // rows per block
  const int g = blockIdx.z, h = blockIdx.y;
  const int gh = g * NHEADS + h;
  A += (size_t)g * asG;
  B += (size_t)g * bsG + (size_t)h * bsH;
  C += (size_t)g * csG + (size_t)h * csH;
  __shared__ float AsT[KT][BR + 4];   // +4 pad keeps rows 16B-aligned, spreads banks
  __shared__ float Bs[KT][NDIM + 4];
  const int tid = threadIdx.x;
  const int tx = tid % TX, ty = tid / TX;
  const int row0b = blockIdx.x * BR;
  const int c0 = tx * 4;
  float acc[RPTY][4];
#pragma unroll
  for (int i = 0; i < RPTY; ++i)
#pragma unroll
    for (int j = 0; j < 4; ++j) acc[i][j] = 0.f;

  for (int kt = 0; kt < KDIM; kt += KT) {
    __syncthreads();
    for (int i = tid; i < BR * (KT / 4); i += 256) {
      const int r = i / (KT / 4), e = i % (KT / 4);
      const float4 v = *(const float4*)(A + (size_t)(row0b + r) * KDIM + kt + e * 4);
      AsT[e * 4 + 0][r] = v.x;
      AsT[e * 4 + 1][r] = v.y;
      AsT[e * 4 + 2][r] = v.z;
      AsT[e * 4 + 3][r] = v.w;
    }
    for (int i = tid; i < KT * (NDIM / 4); i += 256) {
      const int k = i / (NDIM / 4), cc = i % (NDIM / 4);
      *(float4*)&Bs[k][cc * 4] = *(const float4*)(B + (size_t)(kt + k) * NDIM + cc * 4);
    }
    __syncthreads();
#pragma unroll
    for (int k = 0; k < KT; ++k) {
      float a4[RPTY];
      if constexpr (RPTY == 4) {
        const float4 t = *(const float4*)&AsT[k][ty * 4];
        a4[0] = t.x; a4[1] = t.y; a4[2] = t.z; a4[3] = t.w;
      } else {
        const float2 t = *(const float2*)&AsT[k][ty * 2];
        a4[0] = t.x; a4[1] = t.y;
      }
      const float4 bv = *(const float4*)&Bs[k][c0];
      const float b4[4] = {bv.x, bv.y, bv.z, bv.w};
#pragma unroll
      for (int i = 0; i < RPTY; ++i)
#pragma unroll
        for (int j = 0; j < 4; ++j) acc[i][j] += a4[i] * b4[j];
    }
  }
  // epilogue: bias + activation + store
  float b4[4] = {0.f, 0.f, 0.f, 0.f};
  if (bias) {
    const float4 bb = *(const float4*)&bias[c0];
    b4[0] = bb.x; b4[1] = bb.y; b4[2] = bb.z; b4[3] = bb.w;
  }
#pragma unroll
  for (int i = 0; i < RPTY; ++i) {
    const int row = row0b + ty * RPTY + i;
    float4 o;
    float* op = (float*)&o;
#pragma unroll
    for (int j = 0; j < 4; ++j) {
      float v = acc[i][j] + b4[j];
      if (ACT == 1) v = v > 0.f ? v : (__expf(v) - 1.f);  // elu
      op[j] = v;
    }
    *(float4*)&C[(size_t)row * NDIM + c0] = o;
  }
  // fused attention coefficients (pre-activation acc; ACT==0 for GAT gemms)
  if constexpr (COEF) {
    const float* ag = av + (size_t)gh * 2 * NDIM;
    float aS[4], aD[4];
#pragma unroll
    for (int j = 0; j < 4; ++j) { aS[j] = ag[c0 + j]; aD[j] = ag[NDIM + c0 + j]; }
#pragma unroll
    for (int i = 0; i < RPTY; ++i) {
      float s = 0.f, d = 0.f;
#pragma unroll
      for (int j = 0; j < 4; ++j) { s += acc[i][j] * aS[j]; d += acc[i][j] * aD[j]; }
#pragma unroll
      for (int off = TX / 2; off; off >>= 1) {
        s += __shfl_xor(s, off);
        d += __shfl_xor(d, off);
      }
      if (tx == 0) {
        const int row = row0b + ty * RPTY + i;
        fsrc[(size_t)gh * NN + row] = s;
        fdst[(size_t)gh * NN + row] = d;
      }
    }
  }
}

// ---------------------------------------------------------------------------
// Sparse masked softmax + aggregation + ELU for one (n,h,g) per wave.
// O=64: lane = channel. O=32: both half-waves work 2 edges/iter, folded by
// shfl_xor(32). Accumulation unrolled x4 for memory-level parallelism.
template <int O>
__global__ __launch_bounds__(256) void aggregate(const float* __restrict__ Wh,
                                                 const float* __restrict__ fsrc,
                                                 const float* __restrict__ fdst,
                                                 const int* __restrict__ eidx,
                                                 const int* __restrict__ ecnt,
                                                 float* __restrict__ Hout) {
  constexpr int EPI = 64 / O;  // edges per iteration
  __shared__ float wgt[4][CAP];
  __shared__ int midx[4][CAP];
  const int wave = threadIdx.x >> 6;
  const int lane = threadIdx.x & 63;
  const int n = blockIdx.x * 4 + wave;
  const int h = blockIdx.y, g = blockIdx.z;
  const int gh = g * NHEADS + h;
  Wh += (size_t)gh * NN * O;
  const int cnt = ecnt[(size_t)g * NN + n];
  const int* ei = eidx + (size_t)(g * NN + n) * CAP;
  const float fs = fsrc[(size_t)gh * NN + n];
  const float* fd = fdst + (size_t)gh * NN;
  float mx = -3.4e38f;
  for (int j = lane; j < cnt; j += 64) {
    const int m = ei[j];
    float e = fs + fd[m];
    e = e > 0.f ? e : 0.2f * e;  // leaky relu, alpha = 0.2
    midx[wave][j] = m;
    wgt[wave][j] = e;
    mx = fmaxf(mx, e);
  }
  for (int off = 32; off; off >>= 1) mx = fmaxf(mx, __shfl_xor(mx, off));
  float sm = 0.f;
  for (int j = lane; j < cnt; j += 64) {
    const float w = __expf(wgt[wave][j] - mx);
    wgt[wave][j] = w;
    sm += w;
  }
  for (int off = 32; off; off >>= 1) sm += __shfl_xor(sm, off);
  // accumulate: 4 independent partial sums -> 4 loads in flight
  const int eo = lane / O;
  const int o = lane % O;
  float a0 = 0.f, a1 = 0.f, a2 = 0.f, a3 = 0.f;
  int j = eo;
  for (; j + 3 * EPI < cnt; j += 4 * EPI) {
    a0 += wgt[wave][j] * Wh[(size_t)midx[wave][j] * O + o];
    a1 += wgt[wave][j + EPI] * Wh[(size_t)midx[wave][j + EPI] * O + o];
    a2 += wgt[wave][j + 2 * EPI] * Wh[(size_t)midx[wave][j + 2 * EPI] * O + o];
    a3 += wgt[wave][j + 3 * EPI] * Wh[(size_t)midx[wave][j + 3 * EPI] * O + o];
  }
  for (; j < cnt; j += EPI)
    a0 += wgt[wave][j] * Wh[(size_t)midx[wave][j] * O + o];
  float acc = (a0 + a1) + (a2 + a3);
  if (EPI == 2) acc += __shfl_xor(acc, 32);
  if (lane < O) {
    float r = acc / sm;
    r = r > 0.f ? r : (__expf(r) - 1.f);  // elu
    Hout[(size_t)g * NN * (NHEADS * O) + (size_t)n * (NHEADS * O) + h * O + lane] = r;
  }
}

// ---------------------------------------------------------------------------
// Fused tail: o2_g = elu(h2_g @ Wi2 + bi2) for both graphs, logits =
// concat(o2_0, o2_1) @ Wf + bf, log_softmax, plus l1 = mean|Wf|.
// 16 rows/block; thread = (row, k-half, col); k-halves folded by shfl_xor(8).
__global__ __launch_bounds__(256) void tail_fused(const float* __restrict__ h2,
                                                  const float* __restrict__ Wi2,
                                                  const float* __restrict__ bi2,
                                                  const float* __restrict__ Wf,
                                                  const float* __restrict__ bfv,
                                                  float* __restrict__ out) {
  constexpr int K = NHEADS * NHID2;  // 128
  __shared__ float A0[16][K + 4];
  __shared__ float A1[16][K + 4];
  __shared__ float Bs[K][NCLASS];
  __shared__ float WfS[2 * NCLASS][NCLASS];
  __shared__ float cat[16][2 * NCLASS + 1];
  const int tid = threadIdx.x;
  const int row0 = blockIdx.x * 16;
  for (int i = tid; i < 16 * (K / 4); i += 256) {
    const int r = i >> 5, e = i & 31;
    *(float4*)&A0[r][e * 4] = *(const float4*)(h2 + (size_t)(row0 + r) * K + e * 4);
    *(float4*)&A1[r][e * 4] =
        *(const float4*)(h2 + (size_t)NN * K + (size_t)(row0 + r) * K + e * 4);
  }
  ((float4*)Bs)[tid] = ((const float4*)Wi2)[tid];  // 1024 floats = 256 float4
  if (tid < 32) ((float4*)WfS)[tid] = ((const float4*)Wf)[tid];
  __syncthreads();
  const int c = tid & 7;
  const int kk = (tid >> 3) & 1;
  const int r = tid >> 4;
  float s0 = kk ? 0.f : bi2[c], s1 = kk ? 0.f : bi2[c];
#pragma unroll 8
  for (int k = kk * (K / 2); k < (kk + 1) * (K / 2); ++k) {
    s0 += A0[r][k] * Bs[k][c];
    s1 += A1[r][k] * Bs[k][c];
  }
  s0 += __shfl_xor(s0, 8);  // fold k-halves (lane bit 3 = kk)
  s1 += __shfl_xor(s1, 8);
  if (kk == 0) {
    cat[r][c] = s0 > 0.f ? s0 : (__expf(s0) - 1.f);
    cat[r][NCLASS + c] = s1 > 0.f ? s1 : (__expf(s1) - 1.f);
  }
  __syncthreads();
  float logit = bfv[c];
#pragma unroll
  for (int k = 0; k < 2 * NCLASS; ++k) logit += cat[r][k] * WfS[k][c];
  float m = logit;
#pragma unroll
  for (int off = 4; off; off >>= 1) m = fmaxf(m, __shfl_xor(m, off));
  float s = __expf(logit - m);
#pragma unroll
  for (int off = 4; off; off >>= 1) s += __shfl_xor(s, off);
  if (kk == 0) out[(size_t)(row0 + r) * NCLASS + c] = logit - (logf(s) + m);
  if (blockIdx.x == 0 && tid < 64) {  // l1 = mean|Wf| over 128 entries
    float v = fabsf(Wf[tid]) + fabsf(Wf[64 + tid]);
    for (int off = 32; off; off >>= 1) v += __shfl_xor(v, off);
    if (tid == 0) out[NN * NCLASS] = v * (1.f / (2 * NCLASS * NCLASS));
  }
}

// ---------------------------------------------------------------------------
extern "C" void kernel_launch(void* const* d_in, const int* in_sizes, int n_in,
                              void* d_out, int out_size, void* d_ws, size_t ws_size,
                              hipStream_t stream) {
  const float* x = (const float*)d_in[0];
  const float* adj = (const float*)d_in[1];
  const float* W1 = (const float*)d_in[2];
  const float* a1 = (const float*)d_in[3];
  const float* W2 = (const float*)d_in[4];
  const float* a2 = (const float*)d_in[5];
  const float* Wi1 = (const float*)d_in[6];
  const float* bi1 = (const float*)d_in[7];
  const float* Wi2 = (const float*)d_in[8];
  const float* bi2 = (const float*)d_in[9];
  const float* Wf = (const float*)d_in[10];
  const float* bfv = (const float*)d_in[11];
  float* out = (float*)d_out;

  char* ws = (char*)d_ws;
  int* eidx = (int*)ws;     ws += (size_t)NADJ * NN * CAP * 4;             // 4 MB
  int* ecnt = (int*)ws;     ws += (size_t)NADJ * NN * 4;
  float* Wh1 = (float*)ws;  ws += (size_t)NADJ * NHEADS * NN * NHID1 * 4;  // 8 MB
  float* fs1 = (float*)ws;  ws += (size_t)NADJ * NHEADS * NN * 4;
  float* fd1 = (float*)ws;  ws += (size_t)NADJ * NHEADS * NN * 4;
  float* h1 = (float*)ws;   ws += (size_t)NADJ * NN * NHEADS * NHID1 * 4;  // 8 MB
  float* x1 = (float*)ws;   ws += (size_t)NADJ * NN * NHID1 * 4;           // 2 MB
  float* Wh2 = (float*)ws;  ws += (size_t)NADJ * NHEADS * NN * NHID2 * 4;  // 4 MB
  float* fs2 = (float*)ws;  ws += (size_t)NADJ * NHEADS * NN * 4;
  float* fd2 = (float*)ws;  ws += (size_t)NADJ * NHEADS * NN * 4;
  float* h2 = (float*)ws;   ws += (size_t)NADJ * NN * NHEADS * NHID2 * 4;  // 4 MB

  build_edges<<<NADJ * NN / 4, 256, 0, stream>>>(adj, eidx, ecnt);

  // ---- layer 1: GEMM + fused attn coefficients ----
  gemm_tile<NFEAT, NHID1, 4, 0, 1><<<dim3(NN / 64, NHEADS, NADJ), 256, 0, stream>>>(
      x, W1, nullptr, Wh1, a1, fs1, fd1,
      0, (size_t)NFEAT * NHID1, (size_t)NHEADS * NFEAT * NHID1,
      (size_t)NN * NHID1, (size_t)NHEADS * NN * NHID1);
  aggregate<NHID1><<<dim3(NN / 4, NHEADS, NADJ), 256, 0, stream>>>(
      Wh1, fs1, fd1, eidx, ecnt, h1);
  // interlayer linear + elu (BR=32 for full-grid occupancy)
  gemm_tile<NHEADS * NHID1, NHID1, 2, 1, 0><<<dim3(NN / 32, 1, NADJ), 256, 0, stream>>>(
      h1, Wi1, bi1, x1, nullptr, nullptr, nullptr,
      (size_t)NN * NHEADS * NHID1, 0, 0, 0, (size_t)NN * NHID1);

  // ---- layer 2 ----
  gemm_tile<NHID1, NHID2, 4, 0, 1><<<dim3(NN / 128, NHEADS, NADJ), 256, 0, stream>>>(
      x1, W2, nullptr, Wh2, a2, fs2, fd2,
      (size_t)NN * NHID1, (size_t)NHID1 * NHID2, (size_t)NHEADS * NHID1 * NHID2,
      (size_t)NN * NHID2, (size_t)NHEADS * NN * NHID2);
  aggregate<NHID2><<<dim3(NN / 4, NHEADS, NADJ), 256, 0, stream>>>(
      Wh2, fs2, fd2, eidx, ecnt, h2);

  tail_fused<<<NN / 16, 256, 0, stream>>>(h2, Wi2, bi2, Wf, bfv, out);
}

// Round 6
// 101.313 us; speedup vs baseline: 4.9041x; 1.2082x over previous
//
#include <hip/hip_runtime.h>
#include <hip/hip_bf16.h>

#define NN 4096
#define NFEAT 256
#define NHID1 64
#define NHID2 32
#define NCLASS 8
#define NHEADS 4
#define NADJ 2
#define CAP 128

// ---------------------------------------------------------------------------
// Register-blocked tiled GEMM body: C = act(A @ B + bias), optional fused GAT
// attention coefficients (COEF=1): fsrc[row] = Crow.a[0,:], fdst = Crow.a[1,:]
// via shfl_xor tree over the TX lanes of the row. Pointers pre-offset by
// caller (head/graph). sA/sB are LDS scratch (A staged transposed).
template <int KDIM, int NDIM, int RPTY, int ACT, int COEF>
__device__ __forceinline__ void gemm_body(
    const float* __restrict__ A, const float* __restrict__ B,
    const float* __restrict__ bias, float* __restrict__ C,
    const float* __restrict__ ag, float* __restrict__ fsrc,
    float* __restrict__ fdst, const int row0b,
    float* __restrict__ sA, float* __restrict__ sB) {
  constexpr int KT = 32;
  constexpr int TX = NDIM / 4;   // threads along cols
  constexpr int TY = 256 / TX;   // thread groups along rows
  constexpr int BR = TY * RPTY;  // rows per block
  constexpr int LDA = BR + 4;    // pads keep 16B align + spread banks
  constexpr int LDB = NDIM + 4;
  const int tid = threadIdx.x;
  const int tx = tid % TX, ty = tid / TX;
  const int c0 = tx * 4;
  float acc[RPTY][4];
#pragma unroll
  for (int i = 0; i < RPTY; ++i)
#pragma unroll
    for (int j = 0; j < 4; ++j) acc[i][j] = 0.f;

  for (int kt = 0; kt < KDIM; kt += KT) {
    __syncthreads();
    for (int i = tid; i < BR * (KT / 4); i += 256) {
      const int r = i / (KT / 4), e = i % (KT / 4);
      const float4 v = *(const float4*)(A + (size_t)(row0b + r) * KDIM + kt + e * 4);
      sA[(e * 4 + 0) * LDA + r] = v.x;
      sA[(e * 4 + 1) * LDA + r] = v.y;
      sA[(e * 4 + 2) * LDA + r] = v.z;
      sA[(e * 4 + 3) * LDA + r] = v.w;
    }
    for (int i = tid; i < KT * (NDIM / 4); i += 256) {
      const int k = i / (NDIM / 4), cc = i % (NDIM / 4);
      *(float4*)&sB[k * LDB + cc * 4] = *(const float4*)(B + (size_t)(kt + k) * NDIM + cc * 4);
    }
    __syncthreads();
#pragma unroll
    for (int k = 0; k < KT; ++k) {
      float a4[RPTY];
      if constexpr (RPTY == 4) {
        const float4 t = *(const float4*)&sA[k * LDA + ty * 4];
        a4[0] = t.x; a4[1] = t.y; a4[2] = t.z; a4[3] = t.w;
      } else {
        const float2 t = *(const float2*)&sA[k * LDA + ty * 2];
        a4[0] = t.x; a4[1] = t.y;
      }
      const float4 bv = *(const float4*)&sB[k * LDB + c0];
      const float b4[4] = {bv.x, bv.y, bv.z, bv.w};
#pragma unroll
      for (int i = 0; i < RPTY; ++i)
#pragma unroll
        for (int j = 0; j < 4; ++j) acc[i][j] += a4[i] * b4[j];
    }
  }
  float b4[4] = {0.f, 0.f, 0.f, 0.f};
  if (bias) {
    const float4 bb = *(const float4*)&bias[c0];
    b4[0] = bb.x; b4[1] = bb.y; b4[2] = bb.z; b4[3] = bb.w;
  }
#pragma unroll
  for (int i = 0; i < RPTY; ++i) {
    const int row = row0b + ty * RPTY + i;
    float4 o;
    float* op = (float*)&o;
#pragma unroll
    for (int j = 0; j < 4; ++j) {
      float v = acc[i][j] + b4[j];
      if (ACT == 1) v = v > 0.f ? v : (__expf(v) - 1.f);  // elu
      op[j] = v;
    }
    *(float4*)&C[(size_t)row * NDIM + c0] = o;
  }
  if constexpr (COEF) {
    float aS[4], aD[4];
#pragma unroll
    for (int j = 0; j < 4; ++j) { aS[j] = ag[c0 + j]; aD[j] = ag[NDIM + c0 + j]; }
#pragma unroll
    for (int i = 0; i < RPTY; ++i) {
      float s = 0.f, d = 0.f;
#pragma unroll
      for (int j = 0; j < 4; ++j) { s += acc[i][j] * aS[j]; d += acc[i][j] * aD[j]; }
#pragma unroll
      for (int off = TX / 2; off; off >>= 1) {
        s += __shfl_xor(s, off);
        d += __shfl_xor(d, off);
      }
      if (tx == 0) {
        const int row = row0b + ty * RPTY + i;
        fsrc[row] = s;
        fdst[row] = d;
      }
    }
  }
}

// ---------------------------------------------------------------------------
// Fused kernel 1: blocks [0,512) run the L1 GAT GEMM (+coef) — compute-bound;
// blocks [512, 512+2048) build neighbor lists from adj — memory-bound.
// Independent phases overlap across CUs in a single dispatch.
__global__ __launch_bounds__(256) void k1_gemm_edges(
    const float* __restrict__ x, const float* __restrict__ W1,
    const float* __restrict__ a1, float* __restrict__ Wh1,
    float* __restrict__ fs1, float* __restrict__ fd1,
    const float* __restrict__ adj, int* __restrict__ eidx,
    int* __restrict__ ecnt) {
  __shared__ float sA[32 * (64 + 4)];
  __shared__ float sB[32 * (64 + 4)];
  constexpr int NB_GEMM = (NN / 64) * NHEADS * NADJ;  // 512
  if (blockIdx.x < NB_GEMM) {
    int b = blockIdx.x;
    const int tile = b % (NN / 64); b /= (NN / 64);
    const int h = b % NHEADS;
    const int g = b / NHEADS;
    const int gh = g * NHEADS + h;
    gemm_body<NFEAT, NHID1, 4, 0, 1>(
        x, W1 + (size_t)gh * NFEAT * NHID1, nullptr,
        Wh1 + (size_t)gh * NN * NHID1, a1 + (size_t)gh * 2 * NHID1,
        fs1 + (size_t)gh * NN, fd1 + (size_t)gh * NN, tile * 64, sA, sB);
  } else {
    const int wave = threadIdx.x >> 6;
    const int lane = threadIdx.x & 63;
    const int r = (blockIdx.x - NB_GEMM) * 4 + wave;  // g*NN + n
    const float4* row = (const float4*)(adj + (size_t)r * NN);
    int* out = eidx + (size_t)r * CAP;
    int base = 0;
    for (int c = 0; c < NN; c += 256) {
      const float4 v = row[(c >> 2) + lane];
      const int j0 = c + lane * 4;
      const float vt[4] = {v.x, v.y, v.z, v.w};
#pragma unroll
      for (int t = 0; t < 4; ++t) {
        const bool hit = vt[t] > 0.f;
        const unsigned long long m = __ballot(hit);
        if (hit) {
          const int pos = base + __popcll(m & ((1ull << lane) - 1ull));
          if (pos < CAP) out[pos] = j0 + t;
        }
        base += __popcll(m);
      }
    }
    if (lane == 0) ecnt[r] = base < CAP ? base : CAP;
  }
}

// ---------------------------------------------------------------------------
// Standalone GEMM wrapper (interlayer, layer-2 GAT).
template <int KDIM, int NDIM, int RPTY, int ACT, int COEF>
__global__ __launch_bounds__(256) void gemm_tile(
    const float* __restrict__ A, const float* __restrict__ B,
    const float* __restrict__ bias, float* __restrict__ C,
    const float* __restrict__ av, float* __restrict__ fsrc,
    float* __restrict__ fdst,
    size_t asG, size_t bsH, size_t bsG, size_t csH, size_t csG) {
  constexpr int TX = NDIM / 4;
  constexpr int TY = 256 / TX;
  constexpr int BR = TY * RPTY;
  __shared__ float sA[32 * (BR + 4)];
  __shared__ float sB[32 * (NDIM + 4)];
  const int g = blockIdx.z, h = blockIdx.y;
  const int gh = g * NHEADS + h;
  gemm_body<KDIM, NDIM, RPTY, ACT, COEF>(
      A + (size_t)g * asG, B + (size_t)g * bsG + (size_t)h * bsH, bias,
      C + (size_t)g * csG + (size_t)h * csH,
      COEF ? av + (size_t)gh * 2 * NDIM : nullptr,
      COEF ? fsrc + (size_t)gh * NN : nullptr,
      COEF ? fdst + (size_t)gh * NN : nullptr,
      (int)blockIdx.x * BR, sA, sB);
}

// ---------------------------------------------------------------------------
// Sparse masked softmax + aggregation + ELU, one (n,h,g) per wave.
// Gather phase: CPL=O/4 lanes per edge row (float4 each), EPW=64/CPL edges
// concurrently, x4 unrolled -> 16-32 independent 16B loads in flight.
#define GATHER(ACC, JJ)                                                     \
  do {                                                                      \
    const float w_ = wgt[wave][JJ];                                         \
    const float4 v_ = *(const float4*)(Wh + (size_t)midx[wave][JJ] * O + c4); \
    ACC.x += w_ * v_.x; ACC.y += w_ * v_.y;                                 \
    ACC.z += w_ * v_.z; ACC.w += w_ * v_.w;                                 \
  } while (0)

template <int O>
__global__ __launch_bounds__(256) void aggregate(const float* __restrict__ Wh,
                                                 const float* __restrict__ fsrc,
                                                 const float* __restrict__ fdst,
                                                 const int* __restrict__ eidx,
                                                 const int* __restrict__ ecnt,
                                                 float* __restrict__ Hout) {
  constexpr int CPL = O / 4;   // lanes per edge row
  constexpr int EPW = 64 / CPL;  // edges in parallel
  __shared__ float wgt[4][CAP];
  __shared__ int midx[4][CAP];
  const int wave = threadIdx.x >> 6;
  const int lane = threadIdx.x & 63;
  const int n = blockIdx.x * 4 + wave;
  const int h = blockIdx.y, g = blockIdx.z;
  const int gh = g * NHEADS + h;
  Wh += (size_t)gh * NN * O;
  const int cnt = ecnt[(size_t)g * NN + n];
  const int* ei = eidx + (size_t)(g * NN + n) * CAP;
  const float fs = fsrc[(size_t)gh * NN + n];
  const float* fd = fdst + (size_t)gh * NN;
  // masked leaky-relu scores + max
  float mx = -3.4e38f;
  for (int j = lane; j < cnt; j += 64) {
    const int m = ei[j];
    float e = fs + fd[m];
    e = e > 0.f ? e : 0.2f * e;  // leaky relu, alpha = 0.2
    midx[wave][j] = m;
    wgt[wave][j] = e;
    mx = fmaxf(mx, e);
  }
  for (int off = 32; off; off >>= 1) mx = fmaxf(mx, __shfl_xor(mx, off));
  // exp + denom
  float sm = 0.f;
  for (int j = lane; j < cnt; j += 64) {
    const float w = __expf(wgt[wave][j] - mx);
    wgt[wave][j] = w;
    sm += w;
  }
  for (int off = 32; off; off >>= 1) sm += __shfl_xor(sm, off);
  // gather: float4 per lane, EPW edges in parallel, x4 unroll
  const int sub = lane / CPL;
  const int c4 = (lane % CPL) * 4;
  float4 a0 = {0, 0, 0, 0}, a1 = {0, 0, 0, 0}, a2 = {0, 0, 0, 0}, a3 = {0, 0, 0, 0};
  int j = sub;
  for (; j + 3 * EPW < cnt; j += 4 * EPW) {
    GATHER(a0, j);
    GATHER(a1, j + EPW);
    GATHER(a2, j + 2 * EPW);
    GATHER(a3, j + 3 * EPW);
  }
  for (; j < cnt; j += EPW) GATHER(a0, j);
  float4 acc;
  acc.x = (a0.x + a1.x) + (a2.x + a3.x);
  acc.y = (a0.y + a1.y) + (a2.y + a3.y);
  acc.z = (a0.z + a1.z) + (a2.z + a3.z);
  acc.w = (a0.w + a1.w) + (a2.w + a3.w);
#pragma unroll
  for (int off = CPL; off < 64; off <<= 1) {
    acc.x += __shfl_xor(acc.x, off);
    acc.y += __shfl_xor(acc.y, off);
    acc.z += __shfl_xor(acc.z, off);
    acc.w += __shfl_xor(acc.w, off);
  }
  if (lane < CPL) {
    const float inv = 1.f / sm;
    float4 o;
    o.x = acc.x * inv; o.y = acc.y * inv; o.z = acc.z * inv; o.w = acc.w * inv;
    o.x = o.x > 0.f ? o.x : (__expf(o.x) - 1.f);
    o.y = o.y > 0.f ? o.y : (__expf(o.y) - 1.f);
    o.z = o.z > 0.f ? o.z : (__expf(o.z) - 1.f);
    o.w = o.w > 0.f ? o.w : (__expf(o.w) - 1.f);
    *(float4*)&Hout[(size_t)g * NN * (NHEADS * O) + (size_t)n * (NHEADS * O) +
                    h * O + c4] = o;
  }
}

// ---------------------------------------------------------------------------
// Fused tail: o2_g = elu(h2_g @ Wi2 + bi2), logits = concat @ Wf + bf,
// log_softmax, l1 = mean|Wf|.
__global__ __launch_bounds__(256) void tail_fused(const float* __restrict__ h2,
                                                  const float* __restrict__ Wi2,
                                                  const float* __restrict__ bi2,
                                                  const float* __restrict__ Wf,
                                                  const float* __restrict__ bfv,
                                                  float* __restrict__ out) {
  constexpr int K = NHEADS * NHID2;  // 128
  __shared__ float A0[16][K + 4];
  __shared__ float A1[16][K + 4];
  __shared__ float Bs[K][NCLASS];
  __shared__ float WfS[2 * NCLASS][NCLASS];
  __shared__ float cat[16][2 * NCLASS + 1];
  const int tid = threadIdx.x;
  const int row0 = blockIdx.x * 16;
  for (int i = tid; i < 16 * (K / 4); i += 256) {
    const int r = i >> 5, e = i & 31;
    *(float4*)&A0[r][e * 4] = *(const float4*)(h2 + (size_t)(row0 + r) * K + e * 4);
    *(float4*)&A1[r][e * 4] =
        *(const float4*)(h2 + (size_t)NN * K + (size_t)(row0 + r) * K + e * 4);
  }
  ((float4*)Bs)[tid] = ((const float4*)Wi2)[tid];
  if (tid < 32) ((float4*)WfS)[tid] = ((const float4*)Wf)[tid];
  __syncthreads();
  const int c = tid & 7;
  const int kk = (tid >> 3) & 1;
  const int r = tid >> 4;
  float s0 = kk ? 0.f : bi2[c], s1 = kk ? 0.f : bi2[c];
#pragma unroll 8
  for (int k = kk * (K / 2); k < (kk + 1) * (K / 2); ++k) {
    s0 += A0[r][k] * Bs[k][c];
    s1 += A1[r][k] * Bs[k][c];
  }
  s0 += __shfl_xor(s0, 8);
  s1 += __shfl_xor(s1, 8);
  if (kk == 0) {
    cat[r][c] = s0 > 0.f ? s0 : (__expf(s0) - 1.f);
    cat[r][NCLASS + c] = s1 > 0.f ? s1 : (__expf(s1) - 1.f);
  }
  __syncthreads();
  float logit = bfv[c];
#pragma unroll
  for (int k = 0; k < 2 * NCLASS; ++k) logit += cat[r][k] * WfS[k][c];
  float m = logit;
#pragma unroll
  for (int off = 4; off; off >>= 1) m = fmaxf(m, __shfl_xor(m, off));
  float s = __expf(logit - m);
#pragma unroll
  for (int off = 4; off; off >>= 1) s += __shfl_xor(s, off);
  if (kk == 0) out[(size_t)(row0 + r) * NCLASS + c] = logit - (logf(s) + m);
  if (blockIdx.x == 0 && tid < 64) {
    float v = fabsf(Wf[tid]) + fabsf(Wf[64 + tid]);
    for (int off = 32; off; off >>= 1) v += __shfl_xor(v, off);
    if (tid == 0) out[NN * NCLASS] = v * (1.f / (2 * NCLASS * NCLASS));
  }
}

// ---------------------------------------------------------------------------
extern "C" void kernel_launch(void* const* d_in, const int* in_sizes, int n_in,
                              void* d_out, int out_size, void* d_ws, size_t ws_size,
                              hipStream_t stream) {
  const float* x = (const float*)d_in[0];
  const float* adj = (const float*)d_in[1];
  const float* W1 = (const float*)d_in[2];
  const float* a1 = (const float*)d_in[3];
  const float* W2 = (const float*)d_in[4];
  const float* a2 = (const float*)d_in[5];
  const float* Wi1 = (const float*)d_in[6];
  const float* bi1 = (const float*)d_in[7];
  const float* Wi2 = (const float*)d_in[8];
  const float* bi2 = (const float*)d_in[9];
  const float* Wf = (const float*)d_in[10];
  const float* bfv = (const float*)d_in[11];
  float* out = (float*)d_out;

  char* ws = (char*)d_ws;
  int* eidx = (int*)ws;     ws += (size_t)NADJ * NN * CAP * 4;             // 4 MB
  int* ecnt = (int*)ws;     ws += (size_t)NADJ * NN * 4;
  float* Wh1 = (float*)ws;  ws += (size_t)NADJ * NHEADS * NN * NHID1 * 4;  // 8 MB
  float* fs1 = (float*)ws;  ws += (size_t)NADJ * NHEADS * NN * 4;
  float* fd1 = (float*)ws;  ws += (size_t)NADJ * NHEADS * NN * 4;
  float* h1 = (float*)ws;   ws += (size_t)NADJ * NN * NHEADS * NHID1 * 4;  // 8 MB
  float* x1 = (float*)ws;   ws += (size_t)NADJ * NN * NHID1 * 4;           // 2 MB
  float* Wh2 = (float*)ws;  ws += (size_t)NADJ * NHEADS * NN * NHID2 * 4;  // 4 MB
  float* fs2 = (float*)ws;  ws += (size_t)NADJ * NHEADS * NN * 4;
  float* fd2 = (float*)ws;  ws += (size_t)NADJ * NHEADS * NN * 4;
  float* h2 = (float*)ws;   ws += (size_t)NADJ * NN * NHEADS * NHID2 * 4;  // 4 MB

  // K1: L1 GEMM(+coef) overlapped with edge-list build (independent phases).
  k1_gemm_edges<<<512 + NADJ * NN / 4, 256, 0, stream>>>(
      x, W1, a1, Wh1, fs1, fd1, adj, eidx, ecnt);

  aggregate<NHID1><<<dim3(NN / 4, NHEADS, NADJ), 256, 0, stream>>>(
      Wh1, fs1, fd1, eidx, ecnt, h1);

  gemm_tile<NHEADS * NHID1, NHID1, 2, 1, 0><<<dim3(NN / 32, 1, NADJ), 256, 0, stream>>>(
      h1, Wi1, bi1, x1, nullptr, nullptr, nullptr,
      (size_t)NN * NHEADS * NHID1, 0, 0, 0, (size_t)NN * NHID1);

  gemm_tile<NHID1, NHID2, 4, 0, 1><<<dim3(NN / 128, NHEADS, NADJ), 256, 0, stream>>>(
      x1, W2, nullptr, Wh2, a2, fs2, fd2,
      (size_t)NN * NHID1, (size_t)NHID1 * NHID2, (size_t)NHEADS * NHID1 * NHID2,
      (size_t)NN * NHID2, (size_t)NHEADS * NN * NHID2);

  aggregate<NHID2><<<dim3(NN / 4, NHEADS, NADJ), 256, 0, stream>>>(
      Wh2, fs2, fd2, eidx, ecnt, h2);

  tail_fused<<<NN / 16, 256, 0, stream>>>(h2, Wi2, bi2, Wf, bfv, out);
}